// Round 7
// baseline (2625.180 us; speedup 1.0000x reference)
//
#include <hip/hip_runtime.h>

// PointNet++ front-end on MI355X: FPS (B=4, N=16384, NPOINT=1024) + ball query
// nsample=1, radius=0.5. xyz layout [B,3,N]. Output int32 [B,NPOINT,1].
//
// Round-7: kill the register-demotion tax (R1/R2/R4/R5: VGPR_Count always <
// array size -> per-access AGPR/scratch moves). Per-thread register state is
// now only z[16]+dst[16]=32 VGPRs; x,y live in LDS (128 KB dynamic) and are
// streamed per iteration on the DS pipe, which overlaps the VALU scan.
// Centroid coords come from LDS/reduction (no dependent global load).
// Single block per batch (R3: LLC grid-sync costs ~7us/iter, 10x a barrier).

typedef unsigned long long u64;
typedef float v2f __attribute__((ext_vector_type(2)));

constexpr int   N_PTS  = 16384;
constexpr int   NPOINT = 1024;
constexpr int   TB     = 1024;          // 16 waves
constexpr int   KPT    = N_PTS / TB;    // 16 points/thread, strided
constexpr int   NWAVE  = TB / 64;       // 16
constexpr float BIGF   = 1e10f;
constexpr unsigned XY_LDS_BYTES = N_PTS * 8;   // 131072

// Canonical 64-lane DPP reductions (bound_ctrl=false: invalid lanes keep old
// value == identity). Structure HW-verified in rounds 4-6.
__device__ inline unsigned wave_max_u32(unsigned v) {
    int x = (int)v, t;
    t = __builtin_amdgcn_update_dpp(x, x, 0x111, 0xf, 0xf, false);
    x = ((unsigned)x > (unsigned)t) ? x : t;
    t = __builtin_amdgcn_update_dpp(x, x, 0x112, 0xf, 0xf, false);
    x = ((unsigned)x > (unsigned)t) ? x : t;
    t = __builtin_amdgcn_update_dpp(x, x, 0x114, 0xf, 0xf, false);
    x = ((unsigned)x > (unsigned)t) ? x : t;
    t = __builtin_amdgcn_update_dpp(x, x, 0x118, 0xf, 0xf, false);
    x = ((unsigned)x > (unsigned)t) ? x : t;
    t = __builtin_amdgcn_update_dpp(x, x, 0x142, 0xa, 0xf, false);
    x = ((unsigned)x > (unsigned)t) ? x : t;
    t = __builtin_amdgcn_update_dpp(x, x, 0x143, 0xc, 0xf, false);
    x = ((unsigned)x > (unsigned)t) ? x : t;
    return (unsigned)__builtin_amdgcn_readlane(x, 63);
}
__device__ inline unsigned wave_min_u32(unsigned v) {
    int x = (int)v, t;
    t = __builtin_amdgcn_update_dpp(x, x, 0x111, 0xf, 0xf, false);
    x = ((unsigned)x < (unsigned)t) ? x : t;
    t = __builtin_amdgcn_update_dpp(x, x, 0x112, 0xf, 0xf, false);
    x = ((unsigned)x < (unsigned)t) ? x : t;
    t = __builtin_amdgcn_update_dpp(x, x, 0x114, 0xf, 0xf, false);
    x = ((unsigned)x < (unsigned)t) ? x : t;
    t = __builtin_amdgcn_update_dpp(x, x, 0x118, 0xf, 0xf, false);
    x = ((unsigned)x < (unsigned)t) ? x : t;
    t = __builtin_amdgcn_update_dpp(x, x, 0x142, 0xa, 0xf, false);
    x = ((unsigned)x < (unsigned)t) ? x : t;
    t = __builtin_amdgcn_update_dpp(x, x, 0x143, 0xc, 0xf, false);
    x = ((unsigned)x < (unsigned)t) ? x : t;
    return (unsigned)__builtin_amdgcn_readlane(x, 63);
}

__global__ __launch_bounds__(TB)
__attribute__((amdgpu_waves_per_eu(4, 4)))
void fps_lds(const float* __restrict__ xyz,   // [B,3,N]
             int* __restrict__ cent)          // [B,NPOINT]
{
#pragma clang fp contract(off)
    extern __shared__ char lds_raw[];
    v2f* xy = (v2f*)lds_raw;                  // [N_PTS] {x,y} pairs
    __shared__ ulonglong2 sred[2][NWAVE];     // {packed key, z bits}

    const int b    = blockIdx.x;
    const int tid  = threadIdx.x;
    const int wave = tid >> 6;
    const int lane = tid & 63;

    const float* X = xyz + (size_t)b * 3 * N_PTS;
    const float* Y = X + N_PTS;
    const float* Z = X + 2 * N_PTS;

    float zv[KPT], dst[KPT];

    // ---- stage x,y -> LDS; z -> regs; initial argmax over x ----
    float xk[KPT];
#pragma unroll
    for (int k = 0; k < KPT; ++k) {
        const int p = k * TB + tid;           // strided: coalesced
        xk[k] = X[p];
        const float yv = Y[p];
        zv[k] = Z[p];
        xy[p] = (v2f){xk[k], yv};
        dst[k] = BIGF;
    }

    // per-lane max of x
    float m = -1.0f;
#pragma unroll
    for (int k = 0; k < KPT; ++k) m = fmaxf(m, xk[k]);
    // wave value-max (x >= 0: u32 bit order == float order)
    unsigned mvb = wave_max_u32(__float_as_uint(m));
    float    mv  = __uint_as_float(mvb);
    // first-occurrence index: in-lane smallest k, then wave-min of global idx
    unsigned cand = 0xFFFFFFFFu;
    if (m == mv) {
#pragma unroll
        for (int k = KPT - 1; k >= 0; --k)     // descending overwrite -> min k
            if (xk[k] == mv) cand = (unsigned)(k * TB + tid);
    }
    unsigned widx = wave_min_u32(cand);        // wave winner global idx
    // winner z: uniform-k cndmask tree + readlane from owner lane
    {
        const int kwin = (int)(widx >> 10);    // idx / 1024
        float zsel = zv[0];
#pragma unroll
        for (int k = 1; k < KPT; ++k) zsel = (kwin == k) ? zv[k] : zsel;
        const int zw = __builtin_amdgcn_readlane(__float_as_int(zsel),
                                                 (int)(widx & 63u));
        const u64 key = ((u64)mvb << 32) | (unsigned)(N_PTS - 1 - (int)widx);
        if (lane == 0) sred[0][wave] = make_ulonglong2(key, (u64)(unsigned)zw);
    }
    __syncthreads();

    u64 bk; unsigned zbits; int far; float cz; v2f cxy;
    {
        ulonglong2 e = sred[0][0];
        bk = e.x; zbits = (unsigned)e.y;
#pragma unroll
        for (int w = 1; w < NWAVE; ++w) {
            const ulonglong2 o = sred[0][w];
            if (o.x > bk) { bk = o.x; zbits = (unsigned)o.y; }
        }
        far = __builtin_amdgcn_readfirstlane(N_PTS - 1 - (int)(bk & 0xFFFFu));
        cz  = __uint_as_float(zbits);
        cxy = xy[far];                         // uniform addr -> broadcast read
    }

    // ---- main FPS loop: one barrier per iteration ----
    for (int it = 0; it < NPOINT; ++it) {
        if (tid == 0) cent[b * NPOINT + it] = far;   // record PRE-update far
        if (it == NPOINT - 1) break;                 // last update unused

        // stop LICM hoisting the loop-invariant LDS reads into registers
        asm volatile("" ::: "memory");

        float mm = -1.0f;
#pragma unroll
        for (int k = 0; k < KPT; ++k) {
            const v2f pxy = xy[k * TB + tid];        // ds_read_b64
            const v2f dxy = pxy - cxy;               // exact rn, no fma
            const v2f sq  = dxy * dxy;
            const float s2 = sq.x + sq.y;            // dx*dx + dy*dy
            const float dz = zv[k] - cz;
            const float d  = s2 + dz * dz;           // (..) + dz*dz
            const float nd = fminf(dst[k], d);
            dst[k] = nd;
            mm = fmaxf(mm, nd);
        }

        const unsigned mb = wave_max_u32(__float_as_uint(mm));
        const float    mf = __uint_as_float(mb);
        unsigned cd = 0xFFFFFFFFu;
        if (mm == mf) {
#pragma unroll
            for (int k = KPT - 1; k >= 0; --k)
                if (dst[k] == mf) cd = (unsigned)(k * TB + tid);
        }
        const unsigned wi = wave_min_u32(cd);

        const int kwin = (int)(wi >> 10);
        float zsel = zv[0];
#pragma unroll
        for (int k = 1; k < KPT; ++k) zsel = (kwin == k) ? zv[k] : zsel;
        const int zw = __builtin_amdgcn_readlane(__float_as_int(zsel),
                                                 (int)(wi & 63u));
        const u64 key = ((u64)mb << 32) | (unsigned)(N_PTS - 1 - (int)wi);

        const int buf = (it + 1) & 1;                // double buffer: 1 barrier
        if (lane == 0) sred[buf][wave] = make_ulonglong2(key, (u64)(unsigned)zw);
        __syncthreads();

        ulonglong2 e0 = sred[buf][0];
        u64 nk = e0.x; unsigned zb = (unsigned)e0.y;
#pragma unroll
        for (int w = 1; w < NWAVE; ++w) {
            const ulonglong2 o = sred[buf][w];
            if (o.x > nk) { nk = o.x; zb = (unsigned)o.y; }
        }
        far = __builtin_amdgcn_readfirstlane(N_PTS - 1 - (int)(nk & 0xFFFFu));
        cz  = __uint_as_float(zb);
        cxy = xy[far];                               // next centroid x,y
    }
}

// ---------------------------------------------------------------------------
// Fallback single-block FPS (round-2 kernel, known-good 1.82 ms) if the
// dynamic-LDS attribute can't be set.
// ---------------------------------------------------------------------------
__device__ inline u64 pack_key1(float v, int idx) {
    return ((u64)__float_as_uint(v) << 32) | (unsigned)(N_PTS - 1 - idx);
}
__global__ __launch_bounds__(512, 2) void fps_single(
    const float* __restrict__ xyz, int* __restrict__ cent)
{
    constexpr int BL = 512, KP = N_PTS / BL, NW = BL / 64;
    const int b = blockIdx.x, tid = threadIdx.x;
    const float* X = xyz + (size_t)b * 3 * N_PTS;
    const float* Y = X + N_PTS;
    const float* Z = X + 2 * N_PTS;

    float px[KP], py[KP], pz[KP], dst[KP];
#pragma unroll
    for (int k = 0; k < KP; ++k) {
        const int p = tid + k * BL;
        px[k] = X[p]; py[k] = Y[p]; pz[k] = Z[p]; dst[k] = BIGF;
    }
    __shared__ u64 s_key[2][NW];
    const int wave = tid >> 6, lane = tid & 63;

    float bv = px[0]; int bi = tid;
#pragma unroll
    for (int k = 1; k < KP; ++k)
        if (px[k] > bv) { bv = px[k]; bi = tid + k * BL; }
    u64 key = pack_key1(bv, bi);
#pragma unroll
    for (int off = 32; off > 0; off >>= 1) {
        const u64 o = __shfl_xor(key, off);
        if (o > key) key = o;
    }
    if (lane == 0) s_key[0][wave] = key;
    __syncthreads();
    u64 bk = s_key[0][0];
#pragma unroll
    for (int w = 1; w < NW; ++w)
        if (s_key[0][w] > bk) bk = s_key[0][w];
    int far = __builtin_amdgcn_readfirstlane(N_PTS - 1 - (int)(bk & 0xFFFFu));

    for (int it = 0; it < NPOINT; ++it) {
        if (tid == 0) cent[b * NPOINT + it] = far;
        if (it == NPOINT - 1) break;
        const float cx = X[far], cy = Y[far], cz = Z[far];
        float nbv = -1.0f; int nbi = 0;
#pragma unroll
        for (int k = 0; k < KP; ++k) {
            const float dx = __fsub_rn(px[k], cx);
            const float dy = __fsub_rn(py[k], cy);
            const float dz = __fsub_rn(pz[k], cz);
            const float d  = __fadd_rn(
                __fadd_rn(__fmul_rn(dx, dx), __fmul_rn(dy, dy)),
                __fmul_rn(dz, dz));
            const float nd = fminf(dst[k], d);
            dst[k] = nd;
            if (nd > nbv) { nbv = nd; nbi = tid + k * BL; }
        }
        u64 k2 = pack_key1(nbv, nbi);
#pragma unroll
        for (int off = 32; off > 0; off >>= 1) {
            const u64 o = __shfl_xor(k2, off);
            if (o > k2) k2 = o;
        }
        const int buf = (it + 1) & 1;
        if (lane == 0) s_key[buf][wave] = k2;
        __syncthreads();
        u64 b2 = s_key[buf][0];
#pragma unroll
        for (int w = 1; w < NW; ++w)
            if (s_key[buf][w] > b2) b2 = s_key[buf][w];
        far = __builtin_amdgcn_readfirstlane(N_PTS - 1 - (int)(b2 & 0xFFFFu));
    }
}

// ---------------------------------------------------------------------------
// Ball query, nsample=1: one wave per centroid; scan 64-pt chunks from index
// 0, first hit wins. Distance = reference einsum ((-2*dot)+|c|^2)+|p|^2;
// keep-test d <= 0.25 (== !(d > r^2)).
// ---------------------------------------------------------------------------
__global__ __launch_bounds__(256) void ballq_kernel(
    const float* __restrict__ xyz,
    const int* __restrict__ cent,
    int* __restrict__ out)
{
    const int gw   = (blockIdx.x * 256 + threadIdx.x) >> 6;
    const int lane = threadIdx.x & 63;
    const int b = gw / NPOINT;
    const int s = gw % NPOINT;

    const float* X = xyz + (size_t)b * 3 * N_PTS;
    const float* Y = X + N_PTS;
    const float* Z = X + 2 * N_PTS;

    const int ci = cent[b * NPOINT + s];
    const float cx = X[ci], cy = Y[ci], cz = Z[ci];
    const float cn = __fadd_rn(
        __fadd_rn(__fmul_rn(cx, cx), __fmul_rn(cy, cy)), __fmul_rn(cz, cz));

    int res = N_PTS;
    for (int base = 0; base < N_PTS; base += 64) {
        const int p = base + lane;
        const float x = X[p], y = Y[p], z = Z[p];
        const float dot = __fadd_rn(
            __fadd_rn(__fmul_rn(x, cx), __fmul_rn(y, cy)), __fmul_rn(z, cz));
        const float pn = __fadd_rn(
            __fadd_rn(__fmul_rn(x, x), __fmul_rn(y, y)), __fmul_rn(z, z));
        const float d = __fadd_rn(__fadd_rn(__fmul_rn(-2.0f, dot), cn), pn);
        const u64 mask = __ballot(!(d > 0.25f));
        if (mask) {
            res = base + (__ffsll((long long)mask) - 1);
            break;
        }
    }
    if (lane == 0) out[b * NPOINT + s] = res;
}

extern "C" void kernel_launch(void* const* d_in, const int* in_sizes, int n_in,
                              void* d_out, int out_size, void* d_ws, size_t ws_size,
                              hipStream_t stream) {
    const float* xyz = (const float*)d_in[0];
    const int B = in_sizes[1] / 16;            // cls_label is [B,16]
    int* out = (int*)d_out;

    // cent scratch: d_ws if it fits, else alias d_out (safe: ballq wave (b,s)
    // reads cent[b,s] before writing out[b,s], element-wise aliasing only).
    int* cent = (ws_size >= (size_t)B * NPOINT * sizeof(int)) ? (int*)d_ws
                                                              : (int*)d_out;

    // Raise dynamic-LDS cap to 128 KB (immediate host-side call, no stream
    // interaction -> graph-capture safe; idempotent, done every launch).
    const hipError_t e = hipFuncSetAttribute(
        reinterpret_cast<const void*>(fps_lds),
        hipFuncAttributeMaxDynamicSharedMemorySize, XY_LDS_BYTES);

    if (e == hipSuccess) {
        fps_lds<<<B, TB, XY_LDS_BYTES, stream>>>(xyz, cent);
    } else {
        fps_single<<<B, 512, 0, stream>>>(xyz, cent);
    }
    ballq_kernel<<<B * NPOINT / 4, 256, 0, stream>>>(xyz, cent, out);
}